// Round 11
// baseline (340.046 us; speedup 1.0000x reference)
//
#include <hip/hip_runtime.h>
#include <hip/hip_bf16.h>
#include <math.h>

#define EPSF 1e-5f

typedef short bf16x8 __attribute__((ext_vector_type(8)));
typedef float f32x4  __attribute__((ext_vector_type(4)));

#define S_BARRIER   __asm__ volatile("s_barrier" ::: "memory")
#define S_WAITV(n)  __asm__ volatile("s_waitcnt vmcnt(" #n ")" ::: "memory")
#define S_WAITL0    __asm__ volatile("s_waitcnt lgkmcnt(0)" ::: "memory")

__device__ __forceinline__ float gelu_f(float z){
  return 0.5f*z*(1.0f + erff(z*0.70710678118654752f));
}
__device__ __forceinline__ unsigned short f2bf(float f){
  unsigned u = __float_as_uint(f);
  u += 0x7FFFu + ((u >> 16) & 1u);
  return (unsigned short)(u >> 16);
}
__device__ __forceinline__ float bf2f(unsigned short u){
  return __uint_as_float((unsigned)u << 16);
}
__device__ __forceinline__ void gll16(const unsigned short* g, unsigned short* l){
  __builtin_amdgcn_global_load_lds(
    (const __attribute__((address_space(1))) unsigned int*)g,
    (__attribute__((address_space(3))) unsigned int*)l, 16, 0, 0);
}

// ------- all-weight transpose+cast + conv param prep + cm/cnt zero + layer0 LN -------
// blocks 0..255: 64x64 transpose tiles; 256..259: conv params; 260..267: zero cm;
// 268: zero cnt; 269..2316: LayerNorm of x_in -> habf (layer 0)
__global__ void tcast_all_k(const float* __restrict__ wqkv, const float* __restrict__ wout,
                            const float* __restrict__ wfc1, const float* __restrict__ wfc2,
                            unsigned short* __restrict__ oqkv, unsigned short* __restrict__ oout,
                            unsigned short* __restrict__ ofc1, unsigned short* __restrict__ ofc2,
                            const float* __restrict__ wh, const float* __restrict__ bh,
                            const float* __restrict__ wv, const float* __restrict__ bv,
                            const float* __restrict__ g, const float* __restrict__ bb,
                            const float* __restrict__ mm, const float* __restrict__ vv,
                            float* __restrict__ cp, float* __restrict__ cm,
                            int* __restrict__ cnt,
                            const float* __restrict__ x, const float* __restrict__ lg,
                            const float* __restrict__ lb, unsigned short* __restrict__ lnout){
  const int b = blockIdx.x, t = threadIdx.x;
  if (b < 256){
    __shared__ unsigned short lt[64*68];     // stride 68 u16: 8B-aligned rows
    const int l = b >> 7, r = b & 127;
    const float* in; unsigned short* out; int K, N, tk, tn;
    if (r < 48)      { in=wqkv+(long)l*196608; out=oqkv+(long)l*196608; K=256; N=768; tk=r&3;          tn=r>>2; }
    else if (r < 64) { int q=r-48; in=wout+(long)l*65536;  out=oout+(long)l*65536;  K=256; N=256; tk=q&3; tn=q>>2; }
    else if (r < 96) { int q=r-64; in=wfc1+(long)l*131072; out=ofc1+(long)l*131072; K=256; N=512; tk=q&3; tn=q>>2; }
    else             { int q=r-96; in=wfc2+(long)l*131072; out=ofc2+(long)l*131072; K=512; N=256; tk=q&7; tn=q>>3; }
    const int k0 = tk<<6, n0 = tn<<6;
    const int nn = t & 63, kq = t >> 6;
    #pragma unroll
    for (int i=0;i<16;i++){
      const int kl = kq*16 + i;
      lt[nn*68 + kl] = f2bf(in[(long)(k0+kl)*N + n0 + nn]);
    }
    __syncthreads();
    const int k4 = (t & 15) << 2;
    #pragma unroll
    for (int p=0;p<4;p++){
      const int nl = p*16 + (t>>4);
      *reinterpret_cast<ushort4*>(&out[(long)(n0+nl)*K + k0 + k4]) =
        *reinterpret_cast<const ushort4*>(&lt[nl*68 + k4]);
    }
  } else if (b < 260){
    const int j2 = (b-256)*256 + t;
    const int l = j2 >> 9, j = j2 & 511;
    const int o = l*512 + j;
    float sc = g[o]*rsqrtf(vv[o] + EPSF);
    float* c = cp + (long)l*6*512;
    c[0*512+j] = wh[o*3+0];
    c[1*512+j] = wh[o*3+1] + wv[o*3+1];
    c[2*512+j] = wh[o*3+2];
    c[3*512+j] = bh[o] + bv[o];
    c[4*512+j] = sc;
    c[5*512+j] = bb[o] - mm[o]*sc;
  } else if (b < 268){
    cm[(b-260)*256 + t] = 0.f;
  } else if (b == 268){
    if (t < 16) cnt[t] = 0;
  } else {
    const int wv2 = t >> 6, lane = t & 63;
    const int row = (b-269)*4 + wv2;
    const int c4 = lane*4;
    float4 v = *reinterpret_cast<const float4*>(x + (long)row*256 + c4);
    float s  = v.x+v.y+v.z+v.w;
    float s2 = v.x*v.x+v.y*v.y+v.z*v.z+v.w*v.w;
    #pragma unroll
    for (int o=32;o>0;o>>=1){ s += __shfl_xor(s,o); s2 += __shfl_xor(s2,o); }
    const float mu = s*(1.f/256.f);
    const float rstd = rsqrtf(s2*(1.f/256.f) - mu*mu + EPSF);
    float4 gg = *reinterpret_cast<const float4*>(lg + c4);
    float4 bv2 = *reinterpret_cast<const float4*>(lb + c4);
    ushort4 u;
    u.x = f2bf((v.x-mu)*rstd*gg.x + bv2.x);
    u.y = f2bf((v.y-mu)*rstd*gg.y + bv2.y);
    u.z = f2bf((v.z-mu)*rstd*gg.z + bv2.z);
    u.w = f2bf((v.w-mu)*rstd*gg.w + bv2.w);
    *reinterpret_cast<ushort4*>(lnout + (long)row*256 + c4) = u;
  }
}

// ---------------- SE-apply + LayerNorm fused (one row per wave) ----------------
__global__ void seapply_ln_k(float* __restrict__ x, const float* __restrict__ gate,
                             const float* __restrict__ g, const float* __restrict__ b,
                             unsigned short* __restrict__ out){
  const int wv = threadIdx.x >> 6, lane = threadIdx.x & 63;
  const int row = blockIdx.x*4 + wv;
  const int bi = row >> 10;
  const int c4 = lane*4;
  float4 v = *reinterpret_cast<const float4*>(x + (long)row*256 + c4);
  float4 gt = *reinterpret_cast<const float4*>(gate + bi*256 + c4);
  v.x*=gt.x; v.y*=gt.y; v.z*=gt.z; v.w*=gt.w;
  *reinterpret_cast<float4*>(x + (long)row*256 + c4) = v;
  float s  = v.x+v.y+v.z+v.w;
  float s2 = v.x*v.x+v.y*v.y+v.z*v.z+v.w*v.w;
  #pragma unroll
  for (int o=32;o>0;o>>=1){ s += __shfl_xor(s,o); s2 += __shfl_xor(s2,o); }
  const float mu = s*(1.f/256.f);
  const float rstd = rsqrtf(s2*(1.f/256.f) - mu*mu + EPSF);
  float4 gg = *reinterpret_cast<const float4*>(g + c4);
  float4 bb = *reinterpret_cast<const float4*>(b + c4);
  ushort4 u;
  u.x = f2bf((v.x-mu)*rstd*gg.x + bb.x);
  u.y = f2bf((v.y-mu)*rstd*gg.y + bb.y);
  u.z = f2bf((v.z-mu)*rstd*gg.z + bb.z);
  u.w = f2bf((v.w-mu)*rstd*gg.w + bb.w);
  *reinterpret_cast<ushort4*>(out + (long)row*256 + c4) = u;
}

// ---------------- final SE-apply -> d_out fp32 ----------------
__global__ void seapply_out_k(const float* __restrict__ x, const float* __restrict__ gate,
                              float* __restrict__ o){
  long o4 = ((long)blockIdx.x*256 + threadIdx.x)*4;
  float4 v = *reinterpret_cast<const float4*>(x+o4);
  float4 g = *reinterpret_cast<const float4*>(gate + (((o4>>18)<<8) | (o4 & 255)));
  v.x*=g.x; v.y*=g.y; v.z*=g.z; v.w*=g.w;
  *reinterpret_cast<float4*>(o+o4) = v;
}

// ---------------- bf16 MFMA GEMM, dbuf DMA staging, tile BMT x BNT ----------------
// LDS bank-conflict-free: pre-swizzled GLOBAL source chunk (c^(row&7)) + swizzled read;
// gll16 dest stays linear (rule #21). OUT: 0=fp32, 1=bf16, 2=qkv-special (Q scaled
// 0.125; qkb + LDS-transposed coalesced vtb). CS: column sums + fused SE-gate in
// last block per batch (vmcnt-ordered device-scope atomics, NO threadfence — r4/r5 proven).
template<int ACT, bool RES, bool BIAS, int OUT, int BMT, int BNT, bool CS>
__global__ __launch_bounds__(256,2)
void gmm_k(const unsigned short* __restrict__ A,
           const unsigned short* __restrict__ Bt,
           void* __restrict__ Cv, int ldc,
           const float* __restrict__ bias,
           const float* __restrict__ res,
           int K, unsigned short* __restrict__ vtb,
           float* __restrict__ cm,
           const float* __restrict__ w1, const float* __restrict__ w2,
           float* __restrict__ gate, int* __restrict__ cnt)
{
  __shared__ unsigned short As[2][BMT*64];
  __shared__ unsigned short Bs[2][BNT*64];
  float* C = (float*)Cv;
  unsigned short* Cb = (unsigned short*)Cv;
  const int tid  = threadIdx.x;
  const int wave = tid>>6, lane = tid&63;
  constexpr int NI = BMT/32;
  constexpr int NJ = BNT/32;
  constexpr int NDMA = BMT/32 + BNT/32;
  const int wm = (wave>>1)*(16*NI), wn = (wave&1)*(BNT/2);
  const int m0 = blockIdx.y*BMT, n0 = blockIdx.x*BNT;
  const int lrow = lane&15, quad = lane>>4;
  const int sx = lrow & 7;       // read-side XOR (row&7 == lrow&7; wm/wn multiples of 8)

  f32x4 acc[NI][NJ];
  #pragma unroll
  for (int i=0;i<NI;i++)
    #pragma unroll
    for (int j=0;j<NJ;j++)
      #pragma unroll
      for (int r=0;r<4;r++) acc[i][j][r]=0.f;

  auto stage = [&](int kt, int buf){
    const int k0 = kt<<6;
    #pragma unroll
    for (int it2=0; it2<BMT/32; it2++){
      int idx = tid + it2*256;
      int row = idx>>3, c = idx&7;
      gll16(A + (long)(m0+row)*K + k0 + ((c ^ (row&7))<<3), &As[buf][idx*8]);
    }
    #pragma unroll
    for (int it2=0; it2<BNT/32; it2++){
      int idx = tid + it2*256;
      int row = idx>>3, c = idx&7;
      gll16(Bt + (long)(n0+row)*K + k0 + ((c ^ (row&7))<<3), &Bs[buf][idx*8]);
    }
  };

  const int iters = K >> 6;
  stage(0, 0);

  for (int it=0; it<iters; it++){
    const int cur = it & 1;
    if (it+1 < iters){
      stage(it+1, cur^1);
      if constexpr (NDMA==8) { S_WAITV(8); }
      else if constexpr (NDMA==6) { S_WAITV(6); }
      else if constexpr (NDMA==4) { S_WAITV(4); }
      else { S_WAITV(3); }
    } else {
      S_WAITV(0);
    }
    S_BARRIER;

    #pragma unroll
    for (int s=0;s<2;s++){
      bf16x8 a[NI], b[NJ];
      const int ck = s*4 + quad;
      const int cs = (ck ^ sx) << 3;
      #pragma unroll
      for (int i=0;i<NI;i++)
        a[i] = *reinterpret_cast<const bf16x8*>(&As[cur][(wm+16*i+lrow)*64 + cs]);
      #pragma unroll
      for (int j=0;j<NJ;j++)
        b[j] = *reinterpret_cast<const bf16x8*>(&Bs[cur][(wn+16*j+lrow)*64 + cs]);
      #pragma unroll
      for (int i=0;i<NI;i++)
        #pragma unroll
        for (int j=0;j<NJ;j++)
          acc[i][j] = __builtin_amdgcn_mfma_f32_16x16x32_bf16(a[i], b[j], acc[i][j], 0,0,0);
    }
    S_WAITL0;
    S_BARRIER;
  }

  if constexpr (OUT==2){
    if (n0 >= 512){
      // V block: transpose BMT x 128 tile through LDS, coalesced vtb writes
      unsigned short* lt = (unsigned short*)&As[0][0];   // 128 * BMT u16
      #pragma unroll
      for (int i=0;i<NI;i++){
        const int row_l0 = wm + 16*i + quad*4;
        #pragma unroll
        for (int j=0;j<NJ;j++){
          const int col_l = wn + 16*j + lrow;
          #pragma unroll
          for (int r=0;r<4;r++){
            const int row_l = row_l0 + r;
            lt[col_l*BMT + (((row_l>>3) ^ (col_l&7))<<3) + (row_l&7)] = f2bf(acc[i][j][r]);
          }
        }
      }
      __syncthreads();
      const int bb = m0 >> 10, nn0 = m0 & 1023;
      constexpr int CPB = BMT/8;   // 8-token chunks per column
      #pragma unroll
      for (int it2=0; it2<BMT/16; it2++){
        int idx = tid + it2*256;
        int col_l = idx / CPB;
        int row8 = (idx % CPB) * 8;
        uint4 v = *reinterpret_cast<const uint4*>(&lt[col_l*BMT + (((row8>>3) ^ (col_l&7))<<3)]);
        int col = n0 + col_l;
        int h = (col-512) >> 6, d = (col-512) & 63;
        *reinterpret_cast<uint4*>(&vtb[(long)((bb*4+h)*64 + d)*1024 + nn0 + row8]) = v;
      }
      return;
    }
    const float qs = (n0 < 256) ? 0.125f : 1.f;   // fold QK^T scale into Q (exact in bf16)
    #pragma unroll
    for (int i=0;i<NI;i++){
      const int row0 = m0 + wm + 16*i + quad*4;
      #pragma unroll
      for (int j=0;j<NJ;j++){
        const int col = n0 + wn + 16*j + lrow;
        #pragma unroll
        for (int r=0;r<4;r++)
          Cb[(long)(row0+r)*512 + col] = f2bf(acc[i][j][r]*qs);
      }
    }
    return;
  }

  float csum[NJ];
  #pragma unroll
  for (int j=0;j<NJ;j++) csum[j] = 0.f;

  #pragma unroll
  for (int i=0;i<NI;i++){
    const int row0 = m0 + wm + 16*i + quad*4;
    #pragma unroll
    for (int j=0;j<NJ;j++){
      const int col = n0 + wn + 16*j + lrow;
      const float bv = BIAS ? bias[col] : 0.f;
      #pragma unroll
      for (int r=0;r<4;r++){
        const long off = (long)(row0+r)*ldc + col;
        float v = acc[i][j][r] + bv;
        if (RES) v += res[off];
        if (ACT==1) v = gelu_f(v);
        if (CS) csum[j] += v;
        if (OUT==1) Cb[off] = f2bf(v); else C[off] = v;
      }
    }
  }
  if (CS){
    constexpr int BPB = (1024/BMT)*(256/BNT);   // blocks per batch
    float* red = (float*)&As[0][0];
    for (int j = tid; j < BNT; j += 256) red[j] = 0.f;
    __syncthreads();
    #pragma unroll
    for (int j=0;j<NJ;j++)
      atomicAdd(&red[wn + 16*j + lrow], csum[j]);
    __syncthreads();
    const int bb = m0 >> 10;
    for (int j = tid; j < BNT; j += 256)
      atomicAdd(&cm[bb*256 + n0 + j], red[j]);

    // --- fused SE gate: last block of this batch computes gate, resets cm/cnt ---
    // cm atomicAdds are device-scope (execute at coherent point); vmcnt(0) drains this
    // wave's outstanding atomics, syncthreads covers the block. No cache flush.
    S_WAITV(0);
    __syncthreads();
    __shared__ int lastf;
    if (tid==0) lastf = (atomicAdd(&cnt[bb], 1) == BPB-1) ? 1 : 0;
    __syncthreads();
    if (lastf){
      float* sc = (float*)&Bs[0][0];
      float* sh = sc + 256;
      float v = __hip_atomic_load(&cm[bb*256+tid], __ATOMIC_RELAXED, __HIP_MEMORY_SCOPE_AGENT);
      sc[tid] = v*(1.f/1024.f);
      cm[bb*256+tid] = 0.f;
      __syncthreads();
      {
        const int j = tid >> 2, part = tid & 3;
        float a = 0.f;
        #pragma unroll 4
        for (int i=0;i<64;i++){
          const int k = i*4 + part;
          a += sc[k]*w1[k*64+j];
        }
        a += __shfl_xor(a, 1);
        a += __shfl_xor(a, 2);
        if (part == 0) sh[j] = fmaxf(a, 0.f);
      }
      __syncthreads();
      float a = 0.f;
      #pragma unroll 8
      for (int k=0;k<64;k++) a += sh[k]*w2[k*256+tid];
      gate[bb*256+tid] = 1.f/(1.f+__expf(-a));
      if (tid==0) cnt[bb] = 0;
    }
  }
}

// ---------------- MFMA flash attention, no-max softmax, split-K=1, reg-prefetch K/V ----------------
// Q held in registers (invariant across the 16 K-iterations); K/V LDS with named-scalar
// prefetch (rule #20). Row-sum normalization fused -> bf16 o (= habf). LDS 24KB.
// K-tile=64 (measured best: K=128 variant was +1% — attn is NOT barrier-bound, r10).
__global__ __launch_bounds__(256)
void attn_k(const unsigned short* __restrict__ qkb,
            const unsigned short* __restrict__ vtb,
            unsigned short* __restrict__ o){
  const int q0 = blockIdx.x * 64;
  const int bh = blockIdx.y;
  const int b = bh >> 2, h = bh & 3;
  const int tid = threadIdx.x;
  const int wv = tid >> 6;
  const int lane = tid & 63;
  const int l15 = lane & 15, quad = lane >> 4;

  __shared__ unsigned short Ks[64*64];
  __shared__ unsigned short Vt[64*64];
  __shared__ unsigned short Ps[64*64];

  const long rowbase = (long)b*1024;
  const unsigned short* vsrc = vtb + (long)bh*64*1024;

  // Q fragments in registers (Q pre-scaled by 0.125 in the QKV GEMM)
  bf16x8 aq0, aq1;
  {
    const int qrow = q0 + 16*wv + l15;
    aq0 = *reinterpret_cast<const bf16x8*>(qkb + (rowbase + qrow)*512 + h*64 + quad*8);
    aq1 = *reinterpret_cast<const bf16x8*>(qkb + (rowbase + qrow)*512 + h*64 + (4+quad)*8);
  }

  const int row0 = tid >> 3, g0 = tid & 7;
  const int row1 = row0 + 32;
  uint4 kr0, vr0, kr1, vr1;
  auto pre = [&](int k0){
    kr0 = *reinterpret_cast<const uint4*>(qkb + (rowbase + k0 + row0)*512 + 256 + h*64 + g0*8);
    vr0 = *reinterpret_cast<const uint4*>(vsrc + (long)row0*1024 + k0 + g0*8);
    kr1 = *reinterpret_cast<const uint4*>(qkb + (rowbase + k0 + row1)*512 + 256 + h*64 + g0*8);
    vr1 = *reinterpret_cast<const uint4*>(vsrc + (long)row1*1024 + k0 + g0*8);
  };

  float lp[4];
  f32x4 acc[4];
  #pragma unroll
  for (int r=0;r<4;r++) lp[r] = 0.f;
  #pragma unroll
  for (int j=0;j<4;j++)
    #pragma unroll
    for (int r=0;r<4;r++) acc[j][r] = 0.f;

  pre(0);
  for (int k0 = 0; k0 < 1024; k0 += 64){
    // store prefetched K/V tile (prev iter's trailing barrier guarantees LDS free)
    *reinterpret_cast<uint4*>(&Ks[row0*64 + (g0 ^ (row0&7))*8]) = kr0;
    *reinterpret_cast<uint4*>(&Vt[row0*64 + (g0 ^ (row0&7))*8]) = vr0;
    *reinterpret_cast<uint4*>(&Ks[row1*64 + (g0 ^ (row1&7))*8]) = kr1;
    *reinterpret_cast<uint4*>(&Vt[row1*64 + (g0 ^ (row1&7))*8]) = vr1;
    __syncthreads();
    if (k0 + 64 < 1024) pre(k0 + 64);   // overlap next tile's global latency with compute

    f32x4 s[4];
    #pragma unroll
    for (int j=0;j<4;j++)
      #pragma unroll
      for (int r=0;r<4;r++) s[j][r] = 0.f;

    #pragma unroll
    for (int half=0; half<2; half++){
      const int ck = half*4 + quad;
      const bf16x8 a = half ? aq1 : aq0;
      #pragma unroll
      for (int j=0;j<4;j++){
        int krow = 16*j + l15;
        bf16x8 bb = *reinterpret_cast<const bf16x8*>(&Ks[krow*64 + (ck ^ (krow&7))*8]);
        s[j] = __builtin_amdgcn_mfma_f32_16x16x32_bf16(a, bb, s[j], 0,0,0);
      }
    }

    #pragma unroll
    for (int r=0;r<4;r++)
      #pragma unroll
      for (int j=0;j<4;j++){
        float p = __expf(s[j][r]);       // Q pre-scaled by 0.125 in QKV GEMM
        s[j][r] = p;
        lp[r] += p;
      }

    #pragma unroll
    for (int j=0;j<4;j++)
      #pragma unroll
      for (int r=0;r<4;r++){
        int rowq = 16*wv + quad*4 + r;
        int key = l15 + 16*j;
        Ps[rowq*64 + (((key>>3) ^ ((rowq>>2)&7)))*8 + (key&7)] = f2bf(s[j][r]);
      }

    #pragma unroll
    for (int half=0; half<2; half++){
      const int ck = half*4 + quad;
      const int prow = 16*wv + l15;
      bf16x8 a = *reinterpret_cast<const bf16x8*>(&Ps[prow*64 + (ck ^ ((prow>>2)&7))*8]);
      #pragma unroll
      for (int jj=0;jj<4;jj++){
        int drow = 16*jj + l15;
        bf16x8 bb = *reinterpret_cast<const bf16x8*>(&Vt[drow*64 + (ck ^ (drow&7))*8]);
        acc[jj] = __builtin_amdgcn_mfma_f32_16x16x32_bf16(a, bb, acc[jj], 0,0,0);
      }
    }
    __syncthreads();   // all waves done reading Ks/Vt -> next iter may overwrite
  }

  #pragma unroll
  for (int r=0;r<4;r++){
    float l = lp[r];
    l += __shfl_xor(l, 1); l += __shfl_xor(l, 2);
    l += __shfl_xor(l, 4); l += __shfl_xor(l, 8);
    const float inv = 1.f / l;
    const int rloc = q0 + 16*wv + quad*4 + r;
    const long grow = rowbase + rloc;
    #pragma unroll
    for (int jj=0;jj<4;jj++)
      o[grow*256 + h*64 + 16*jj + l15] = f2bf(acc[jj][r]*inv);
  }
}

// ---------------- depthwise conv + BN + GELU, vectorized ----------------
__global__ void conv_bf_k(const unsigned short* __restrict__ y, unsigned short* __restrict__ z,
                          const float* __restrict__ cp)
{
  const int t = threadIdx.x;
  const int rr = t >> 6;
  const int row = blockIdx.x*4 + rr;
  const int n = row & 1023;
  const int c8 = (t & 63) * 8;
  const long base = (long)row*512 + c8;

  uint4 uc = *reinterpret_cast<const uint4*>(y + base);
  uint4 um = (n>0)    ? *reinterpret_cast<const uint4*>(y + base - 512) : uint4{0,0,0,0};
  uint4 up = (n<1023) ? *reinterpret_cast<const uint4*>(y + base + 512) : uint4{0,0,0,0};
  const unsigned short* yc = reinterpret_cast<const unsigned short*>(&uc);
  const unsigned short* ym = reinterpret_cast<const unsigned short*>(&um);
  const unsigned short* yp = reinterpret_cast<const unsigned short*>(&up);

  float c0[8], c1[8], c2[8], c3[8], s5[8], b5[8];
  #pragma unroll
  for (int q=0;q<8;q+=4){
    *reinterpret_cast<float4*>(&c0[q]) = *reinterpret_cast<const float4*>(cp + 0*512 + c8 + q);
    *reinterpret_cast<float4*>(&c1[q]) = *reinterpret_cast<const float4*>(cp + 1*512 + c8 + q);
    *reinterpret_cast<float4*>(&c2[q]) = *reinterpret_cast<const float4*>(cp + 2*512 + c8 + q);
    *reinterpret_cast<float4*>(&c3[q]) = *reinterpret_cast<const float4*>(cp + 3*512 + c8 + q);
    *reinterpret_cast<float4*>(&s5[q]) = *reinterpret_cast<const float4*>(cp + 4*512 + c8 + q);
    *reinterpret_cast<float4*>(&b5[q]) = *reinterpret_cast<const float4*>(cp + 5*512 + c8 + q);
  }

  unsigned short outv[8];
  #pragma unroll
  for (int q=0;q<8;q++){
    float zz = c0[q]*bf2f(ym[q]) + c1[q]*bf2f(yc[q]) + c2[q]*bf2f(yp[q]) + c3[q];
    zz = zz*s5[q] + b5[q];
    outv[q] = f2bf(gelu_f(zz));
  }
  *reinterpret_cast<uint4*>(z + base) = *reinterpret_cast<uint4*>(outv);
}

extern "C" void kernel_launch(void* const* d_in, const int* in_sizes, int n_in,
                              void* d_out, int out_size, void* d_ws, size_t ws_size,
                              hipStream_t stream)
{
  const float* x_in  = (const float*)d_in[0];
  const float* ln1_g = (const float*)d_in[1];
  const float* ln1_b = (const float*)d_in[2];
  const float* w_qkv = (const float*)d_in[3];
  const float* w_out = (const float*)d_in[4];
  const float* b_out = (const float*)d_in[5];
  const float* ln2_g = (const float*)d_in[6];
  const float* ln2_b = (const float*)d_in[7];
  const float* w_fc1 = (const float*)d_in[8];
  const float* b_fc1 = (const float*)d_in[9];
  const float* wh    = (const float*)d_in[10];
  const float* bh    = (const float*)d_in[11];
  const float* wv    = (const float*)d_in[12];
  const float* bv    = (const float*)d_in[13];
  const float* bn_g  = (const float*)d_in[14];
  const float* bn_b  = (const float*)d_in[15];
  const float* bn_m  = (const float*)d_in[16];
  const float* bn_v  = (const float*)d_in[17];
  const float* w_fc2 = (const float*)d_in[18];
  const float* b_fc2 = (const float*)d_in[19];
  const float* ls_w1 = (const float*)d_in[20];
  const float* ls_w2 = (const float*)d_in[21];

  float* ws   = (float*)d_ws;
  float* xbuf = ws;                        // 2,097,152 fl
  float* cm   = xbuf + 2097152;            // 2,048
  float* gate = cm + 2048;                 // 2,048
  float* cpar = gate + 2048;               // 6,144  [2][6][512]
  int*   cnt  = (int*)(cpar + 6144);       // 16 ints
  unsigned short* habf = (unsigned short*)(cpar + 6144 + 16); // 2,097,152 u16
  unsigned short* qkb  = habf + 2097152;                      // 4,194,304 u16
  unsigned short* vtb  = qkb  + 4194304;                      // 2,097,152 u16
  unsigned short* ybf  = vtb  + 2097152;                      // 4,194,304 u16
  unsigned short* zbf  = ybf  + 4194304;                      // 4,194,304 u16
  unsigned short* wqkv_t = zbf + 4194304;
  unsigned short* wout_t = wqkv_t + 393216;
  unsigned short* wfc1_t = wout_t + 131072;
  unsigned short* wfc2_t = wfc1_t + 262144;

  tcast_all_k<<<2317,256,0,stream>>>(w_qkv, w_out, w_fc1, w_fc2,
                                     wqkv_t, wout_t, wfc1_t, wfc2_t,
                                     wh, bh, wv, bv, bn_g, bn_b, bn_m, bn_v, cpar, cm, cnt,
                                     x_in, ln1_g, ln1_b, habf);

  for (int l=0;l<2;l++){
    const float* bout_l = b_out + l*256;
    const float* bfc1_l = b_fc1 + l*512;
    const float* bfc2_l = b_fc2 + l*256;
    const float* lw1_l  = ls_w1 + (long)l*256*64;
    const float* lw2_l  = ls_w2 + (long)l*64*256;
    const float* resx   = (l==0) ? x_in : xbuf;

    // --- MHSA ---
    gmm_k<0,false,false,2,64,128,false><<<dim3(6,128),256,0,stream>>>(
        habf, wqkv_t + (long)l*768*256, (void*)qkb, 512, nullptr, nullptr, 256, vtb,
        nullptr, nullptr, nullptr, nullptr, nullptr);
    attn_k<<<dim3(16,32),256,0,stream>>>(qkb, vtb, habf);
    gmm_k<0,true,true,0,32,64,true><<<dim3(4,256),256,0,stream>>>(
        habf, wout_t + (long)l*256*256, (void*)xbuf, 256, bout_l, resx, 256, nullptr,
        cm, lw1_l, lw2_l, gate, cnt);

    seapply_ln_k<<<2048,256,0,stream>>>(xbuf, gate, ln2_g + l*256, ln2_b + l*256, habf);

    // --- MLP ---
    gmm_k<1,false,true,1,64,64,false><<<dim3(8,128),256,0,stream>>>(
        habf, wfc1_t + (long)l*512*256, (void*)ybf, 512, bfc1_l, nullptr, 256, nullptr,
        nullptr, nullptr, nullptr, nullptr, nullptr);
    conv_bf_k<<<2048,256,0,stream>>>(ybf, zbf, cpar + (long)l*6*512);
    gmm_k<0,true,true,0,32,64,true><<<dim3(4,256),256,0,stream>>>(
        zbf, wfc2_t + (long)l*256*512, (void*)xbuf, 256, bfc2_l, xbuf, 512, nullptr,
        cm, lw1_l, lw2_l, gate, cnt);

    if (l==0)
      seapply_ln_k<<<2048,256,0,stream>>>(xbuf, gate, ln1_g + 256, ln1_b + 256, habf);
    else
      seapply_out_k<<<2048,256,0,stream>>>(xbuf, gate, (float*)d_out);
  }
}

// Round 12
// 297.570 us; speedup vs baseline: 1.1427x; 1.1427x over previous
//
#include <hip/hip_runtime.h>
#include <hip/hip_bf16.h>
#include <math.h>

#define EPSF 1e-5f

typedef short bf16x8 __attribute__((ext_vector_type(8)));
typedef float f32x4  __attribute__((ext_vector_type(4)));

#define S_BARRIER   __asm__ volatile("s_barrier" ::: "memory")
#define S_WAITV(n)  __asm__ volatile("s_waitcnt vmcnt(" #n ")" ::: "memory")
#define S_WAITL0    __asm__ volatile("s_waitcnt lgkmcnt(0)" ::: "memory")

__device__ __forceinline__ float gelu_f(float z){
  return 0.5f*z*(1.0f + erff(z*0.70710678118654752f));
}
__device__ __forceinline__ unsigned short f2bf(float f){
  unsigned u = __float_as_uint(f);
  u += 0x7FFFu + ((u >> 16) & 1u);
  return (unsigned short)(u >> 16);
}
__device__ __forceinline__ float bf2f(unsigned short u){
  return __uint_as_float((unsigned)u << 16);
}
__device__ __forceinline__ void gll16(const unsigned short* g, unsigned short* l){
  __builtin_amdgcn_global_load_lds(
    (const __attribute__((address_space(1))) unsigned int*)g,
    (__attribute__((address_space(3))) unsigned int*)l, 16, 0, 0);
}

// ------- all-weight transpose+cast + conv param prep + cm zero + layer0 LN -------
__global__ void tcast_all_k(const float* __restrict__ wqkv, const float* __restrict__ wout,
                            const float* __restrict__ wfc1, const float* __restrict__ wfc2,
                            unsigned short* __restrict__ oqkv, unsigned short* __restrict__ oout,
                            unsigned short* __restrict__ ofc1, unsigned short* __restrict__ ofc2,
                            const float* __restrict__ wh, const float* __restrict__ bh,
                            const float* __restrict__ wv, const float* __restrict__ bv,
                            const float* __restrict__ g, const float* __restrict__ bb,
                            const float* __restrict__ mm, const float* __restrict__ vv,
                            float* __restrict__ cp, float* __restrict__ cm,
                            const float* __restrict__ x, const float* __restrict__ lg,
                            const float* __restrict__ lb, unsigned short* __restrict__ lnout){
  const int b = blockIdx.x, t = threadIdx.x;
  if (b < 256){
    __shared__ unsigned short lt[64*68];     // stride 68 u16: 8B-aligned rows
    const int l = b >> 7, r = b & 127;
    const float* in; unsigned short* out; int K, N, tk, tn;
    if (r < 48)      { in=wqkv+(long)l*196608; out=oqkv+(long)l*196608; K=256; N=768; tk=r&3;          tn=r>>2; }
    else if (r < 64) { int q=r-48; in=wout+(long)l*65536;  out=oout+(long)l*65536;  K=256; N=256; tk=q&3; tn=q>>2; }
    else if (r < 96) { int q=r-64; in=wfc1+(long)l*131072; out=ofc1+(long)l*131072; K=256; N=512; tk=q&3; tn=q>>2; }
    else             { int q=r-96; in=wfc2+(long)l*131072; out=ofc2+(long)l*131072; K=512; N=256; tk=q&7; tn=q>>3; }
    const int k0 = tk<<6, n0 = tn<<6;
    const int nn = t & 63, kq = t >> 6;
    #pragma unroll
    for (int i=0;i<16;i++){
      const int kl = kq*16 + i;
      lt[nn*68 + kl] = f2bf(in[(long)(k0+kl)*N + n0 + nn]);
    }
    __syncthreads();
    const int k4 = (t & 15) << 2;
    #pragma unroll
    for (int p=0;p<4;p++){
      const int nl = p*16 + (t>>4);
      *reinterpret_cast<ushort4*>(&out[(long)(n0+nl)*K + k0 + k4]) =
        *reinterpret_cast<const ushort4*>(&lt[nl*68 + k4]);
    }
  } else if (b < 260){
    const int j2 = (b-256)*256 + t;
    const int l = j2 >> 9, j = j2 & 511;
    const int o = l*512 + j;
    float sc = g[o]*rsqrtf(vv[o] + EPSF);
    float* c = cp + (long)l*6*512;
    c[0*512+j] = wh[o*3+0];
    c[1*512+j] = wh[o*3+1] + wv[o*3+1];
    c[2*512+j] = wh[o*3+2];
    c[3*512+j] = bh[o] + bv[o];
    c[4*512+j] = sc;
    c[5*512+j] = bb[o] - mm[o]*sc;
  } else if (b < 268){
    cm[(b-260)*256 + t] = 0.f;
  } else {
    const int wv2 = t >> 6, lane = t & 63;
    const int row = (b-268)*4 + wv2;
    const int c4 = lane*4;
    float4 v = *reinterpret_cast<const float4*>(x + (long)row*256 + c4);
    float s  = v.x+v.y+v.z+v.w;
    float s2 = v.x*v.x+v.y*v.y+v.z*v.z+v.w*v.w;
    #pragma unroll
    for (int o=32;o>0;o>>=1){ s += __shfl_xor(s,o); s2 += __shfl_xor(s2,o); }
    const float mu = s*(1.f/256.f);
    const float rstd = rsqrtf(s2*(1.f/256.f) - mu*mu + EPSF);
    float4 gg = *reinterpret_cast<const float4*>(lg + c4);
    float4 bv2 = *reinterpret_cast<const float4*>(lb + c4);
    ushort4 u;
    u.x = f2bf((v.x-mu)*rstd*gg.x + bv2.x);
    u.y = f2bf((v.y-mu)*rstd*gg.y + bv2.y);
    u.z = f2bf((v.z-mu)*rstd*gg.z + bv2.z);
    u.w = f2bf((v.w-mu)*rstd*gg.w + bv2.w);
    *reinterpret_cast<ushort4*>(lnout + (long)row*256 + c4) = u;
  }
}

// ---------------- SE-apply + LayerNorm fused (one row per wave) ----------------
__global__ void seapply_ln_k(float* __restrict__ x, const float* __restrict__ gate,
                             const float* __restrict__ g, const float* __restrict__ b,
                             unsigned short* __restrict__ out){
  const int wv = threadIdx.x >> 6, lane = threadIdx.x & 63;
  const int row = blockIdx.x*4 + wv;
  const int bi = row >> 10;
  const int c4 = lane*4;
  float4 v = *reinterpret_cast<const float4*>(x + (long)row*256 + c4);
  float4 gt = *reinterpret_cast<const float4*>(gate + bi*256 + c4);
  v.x*=gt.x; v.y*=gt.y; v.z*=gt.z; v.w*=gt.w;
  *reinterpret_cast<float4*>(x + (long)row*256 + c4) = v;
  float s  = v.x+v.y+v.z+v.w;
  float s2 = v.x*v.x+v.y*v.y+v.z*v.z+v.w*v.w;
  #pragma unroll
  for (int o=32;o>0;o>>=1){ s += __shfl_xor(s,o); s2 += __shfl_xor(s2,o); }
  const float mu = s*(1.f/256.f);
  const float rstd = rsqrtf(s2*(1.f/256.f) - mu*mu + EPSF);
  float4 gg = *reinterpret_cast<const float4*>(g + c4);
  float4 bb = *reinterpret_cast<const float4*>(b + c4);
  ushort4 u;
  u.x = f2bf((v.x-mu)*rstd*gg.x + bb.x);
  u.y = f2bf((v.y-mu)*rstd*gg.y + bb.y);
  u.z = f2bf((v.z-mu)*rstd*gg.z + bb.z);
  u.w = f2bf((v.w-mu)*rstd*gg.w + bb.w);
  *reinterpret_cast<ushort4*>(out + (long)row*256 + c4) = u;
}

// ---------------- final SE-apply -> d_out fp32 ----------------
__global__ void seapply_out_k(const float* __restrict__ x, const float* __restrict__ gate,
                              float* __restrict__ o){
  long o4 = ((long)blockIdx.x*256 + threadIdx.x)*4;
  float4 v = *reinterpret_cast<const float4*>(x+o4);
  float4 g = *reinterpret_cast<const float4*>(gate + (((o4>>18)<<8) | (o4 & 255)));
  v.x*=g.x; v.y*=g.y; v.z*=g.z; v.w*=g.w;
  *reinterpret_cast<float4*>(o+o4) = v;
}

// ---------------- bf16 MFMA GEMM, dbuf DMA staging, tile BMT x BNT ----------------
// LDS bank-conflict-free: pre-swizzled GLOBAL source chunk (c^(row&7)) + swizzled read;
// gll16 dest stays linear (rule #21). OUT: 0=fp32, 1=bf16, 2=qkv-special (Q scaled
// 0.125; qkb + LDS-transposed coalesced vtb). CS: column sums into cm.
// Min-waves by LDS footprint: 24/32KB tiles -> 4 blocks/CU, 48KB -> 3 (VGPR 52 << caps).
template<int ACT, bool RES, bool BIAS, int OUT, int BMT, int BNT, bool CS>
__global__ __launch_bounds__(256, ((BMT+BNT)*256 <= 32768) ? 4 : (((BMT+BNT)*256 <= 49152) ? 3 : 2))
void gmm_k(const unsigned short* __restrict__ A,
           const unsigned short* __restrict__ Bt,
           void* __restrict__ Cv, int ldc,
           const float* __restrict__ bias,
           const float* __restrict__ res,
           int K, unsigned short* __restrict__ vtb,
           float* __restrict__ cm)
{
  __shared__ unsigned short As[2][BMT*64];
  __shared__ unsigned short Bs[2][BNT*64];
  float* C = (float*)Cv;
  unsigned short* Cb = (unsigned short*)Cv;
  const int tid  = threadIdx.x;
  const int wave = tid>>6, lane = tid&63;
  constexpr int NI = BMT/32;
  constexpr int NJ = BNT/32;
  constexpr int NDMA = BMT/32 + BNT/32;
  const int wm = (wave>>1)*(16*NI), wn = (wave&1)*(BNT/2);
  const int m0 = blockIdx.y*BMT, n0 = blockIdx.x*BNT;
  const int lrow = lane&15, quad = lane>>4;
  const int sx = lrow & 7;       // read-side XOR (row&7 == lrow&7; wm/wn multiples of 8)

  f32x4 acc[NI][NJ];
  #pragma unroll
  for (int i=0;i<NI;i++)
    #pragma unroll
    for (int j=0;j<NJ;j++)
      #pragma unroll
      for (int r=0;r<4;r++) acc[i][j][r]=0.f;

  auto stage = [&](int kt, int buf){
    const int k0 = kt<<6;
    #pragma unroll
    for (int it2=0; it2<BMT/32; it2++){
      int idx = tid + it2*256;
      int row = idx>>3, c = idx&7;
      gll16(A + (long)(m0+row)*K + k0 + ((c ^ (row&7))<<3), &As[buf][idx*8]);
    }
    #pragma unroll
    for (int it2=0; it2<BNT/32; it2++){
      int idx = tid + it2*256;
      int row = idx>>3, c = idx&7;
      gll16(Bt + (long)(n0+row)*K + k0 + ((c ^ (row&7))<<3), &Bs[buf][idx*8]);
    }
  };

  const int iters = K >> 6;
  stage(0, 0);

  for (int it=0; it<iters; it++){
    const int cur = it & 1;
    if (it+1 < iters){
      stage(it+1, cur^1);
      if constexpr (NDMA==8) { S_WAITV(8); }
      else if constexpr (NDMA==6) { S_WAITV(6); }
      else if constexpr (NDMA==4) { S_WAITV(4); }
      else { S_WAITV(3); }
    } else {
      S_WAITV(0);
    }
    S_BARRIER;

    #pragma unroll
    for (int s=0;s<2;s++){
      bf16x8 a[NI], b[NJ];
      const int ck = s*4 + quad;
      const int cs = (ck ^ sx) << 3;
      #pragma unroll
      for (int i=0;i<NI;i++)
        a[i] = *reinterpret_cast<const bf16x8*>(&As[cur][(wm+16*i+lrow)*64 + cs]);
      #pragma unroll
      for (int j=0;j<NJ;j++)
        b[j] = *reinterpret_cast<const bf16x8*>(&Bs[cur][(wn+16*j+lrow)*64 + cs]);
      #pragma unroll
      for (int i=0;i<NI;i++)
        #pragma unroll
        for (int j=0;j<NJ;j++)
          acc[i][j] = __builtin_amdgcn_mfma_f32_16x16x32_bf16(a[i], b[j], acc[i][j], 0,0,0);
    }
    S_WAITL0;
    S_BARRIER;
  }

  if constexpr (OUT==2){
    if (n0 >= 512){
      // V block: transpose BMT x 128 tile through LDS, coalesced vtb writes
      unsigned short* lt = (unsigned short*)&As[0][0];   // 128 * BMT u16
      #pragma unroll
      for (int i=0;i<NI;i++){
        const int row_l0 = wm + 16*i + quad*4;
        #pragma unroll
        for (int j=0;j<NJ;j++){
          const int col_l = wn + 16*j + lrow;
          #pragma unroll
          for (int r=0;r<4;r++){
            const int row_l = row_l0 + r;
            lt[col_l*BMT + (((row_l>>3) ^ (col_l&7))<<3) + (row_l&7)] = f2bf(acc[i][j][r]);
          }
        }
      }
      __syncthreads();
      const int bb = m0 >> 10, nn0 = m0 & 1023;
      constexpr int CPB = BMT/8;   // 8-token chunks per column
      #pragma unroll
      for (int it2=0; it2<BMT/16; it2++){
        int idx = tid + it2*256;
        int col_l = idx / CPB;
        int row8 = (idx % CPB) * 8;
        uint4 v = *reinterpret_cast<const uint4*>(&lt[col_l*BMT + (((row8>>3) ^ (col_l&7))<<3)]);
        int col = n0 + col_l;
        int h = (col-512) >> 6, d = (col-512) & 63;
        *reinterpret_cast<uint4*>(&vtb[(long)((bb*4+h)*64 + d)*1024 + nn0 + row8]) = v;
      }
      return;
    }
    const float qs = (n0 < 256) ? 0.125f : 1.f;   // fold QK^T scale into Q (exact in bf16)
    #pragma unroll
    for (int i=0;i<NI;i++){
      const int row0 = m0 + wm + 16*i + quad*4;
      #pragma unroll
      for (int j=0;j<NJ;j++){
        const int col = n0 + wn + 16*j + lrow;
        #pragma unroll
        for (int r=0;r<4;r++)
          Cb[(long)(row0+r)*512 + col] = f2bf(acc[i][j][r]*qs);
      }
    }
    return;
  }

  float csum[NJ];
  #pragma unroll
  for (int j=0;j<NJ;j++) csum[j] = 0.f;

  #pragma unroll
  for (int i=0;i<NI;i++){
    const int row0 = m0 + wm + 16*i + quad*4;
    #pragma unroll
    for (int j=0;j<NJ;j++){
      const int col = n0 + wn + 16*j + lrow;
      const float bv = BIAS ? bias[col] : 0.f;
      #pragma unroll
      for (int r=0;r<4;r++){
        const long off = (long)(row0+r)*ldc + col;
        float v = acc[i][j][r] + bv;
        if (RES) v += res[off];
        if (ACT==1) v = gelu_f(v);
        if (CS) csum[j] += v;
        if (OUT==1) Cb[off] = f2bf(v); else C[off] = v;
      }
    }
  }
  if (CS){
    float* red = (float*)&As[0][0];
    for (int j = tid; j < BNT; j += 256) red[j] = 0.f;
    __syncthreads();
    #pragma unroll
    for (int j=0;j<NJ;j++)
      atomicAdd(&red[wn + 16*j + lrow], csum[j]);
    __syncthreads();
    const int bb = m0 >> 10;
    for (int j = tid; j < BNT; j += 256)
      atomicAdd(&cm[bb*256 + n0 + j], red[j]);
  }
}

// ---------------- MFMA flash attention, no-max softmax, split-K=1, reg-prefetch K/V ----------------
// Q held in registers (invariant across the 16 K-iterations); K/V LDS with named-scalar
// prefetch (rule #20). Row-sum normalization fused -> bf16 o (= habf). LDS 24KB.
// K-tile=64 (measured best: K=128 was +1%, r10; fused-gate −40µs, r11 — both refuted).
__global__ __launch_bounds__(256)
void attn_k(const unsigned short* __restrict__ qkb,
            const unsigned short* __restrict__ vtb,
            unsigned short* __restrict__ o){
  const int q0 = blockIdx.x * 64;
  const int bh = blockIdx.y;
  const int b = bh >> 2, h = bh & 3;
  const int tid = threadIdx.x;
  const int wv = tid >> 6;
  const int lane = tid & 63;
  const int l15 = lane & 15, quad = lane >> 4;

  __shared__ unsigned short Ks[64*64];
  __shared__ unsigned short Vt[64*64];
  __shared__ unsigned short Ps[64*64];

  const long rowbase = (long)b*1024;
  const unsigned short* vsrc = vtb + (long)bh*64*1024;

  // Q fragments in registers (Q pre-scaled by 0.125 in the QKV GEMM)
  bf16x8 aq0, aq1;
  {
    const int qrow = q0 + 16*wv + l15;
    aq0 = *reinterpret_cast<const bf16x8*>(qkb + (rowbase + qrow)*512 + h*64 + quad*8);
    aq1 = *reinterpret_cast<const bf16x8*>(qkb + (rowbase + qrow)*512 + h*64 + (4+quad)*8);
  }

  const int row0 = tid >> 3, g0 = tid & 7;
  const int row1 = row0 + 32;
  uint4 kr0, vr0, kr1, vr1;
  auto pre = [&](int k0){
    kr0 = *reinterpret_cast<const uint4*>(qkb + (rowbase + k0 + row0)*512 + 256 + h*64 + g0*8);
    vr0 = *reinterpret_cast<const uint4*>(vsrc + (long)row0*1024 + k0 + g0*8);
    kr1 = *reinterpret_cast<const uint4*>(qkb + (rowbase + k0 + row1)*512 + 256 + h*64 + g0*8);
    vr1 = *reinterpret_cast<const uint4*>(vsrc + (long)row1*1024 + k0 + g0*8);
  };

  float lp[4];
  f32x4 acc[4];
  #pragma unroll
  for (int r=0;r<4;r++) lp[r] = 0.f;
  #pragma unroll
  for (int j=0;j<4;j++)
    #pragma unroll
    for (int r=0;r<4;r++) acc[j][r] = 0.f;

  pre(0);
  for (int k0 = 0; k0 < 1024; k0 += 64){
    // store prefetched K/V tile (prev iter's trailing barrier guarantees LDS free)
    *reinterpret_cast<uint4*>(&Ks[row0*64 + (g0 ^ (row0&7))*8]) = kr0;
    *reinterpret_cast<uint4*>(&Vt[row0*64 + (g0 ^ (row0&7))*8]) = vr0;
    *reinterpret_cast<uint4*>(&Ks[row1*64 + (g0 ^ (row1&7))*8]) = kr1;
    *reinterpret_cast<uint4*>(&Vt[row1*64 + (g0 ^ (row1&7))*8]) = vr1;
    __syncthreads();
    if (k0 + 64 < 1024) pre(k0 + 64);   // overlap next tile's global latency with compute

    f32x4 s[4];
    #pragma unroll
    for (int j=0;j<4;j++)
      #pragma unroll
      for (int r=0;r<4;r++) s[j][r] = 0.f;

    #pragma unroll
    for (int half=0; half<2; half++){
      const int ck = half*4 + quad;
      const bf16x8 a = half ? aq1 : aq0;
      #pragma unroll
      for (int j=0;j<4;j++){
        int krow = 16*j + l15;
        bf16x8 bb = *reinterpret_cast<const bf16x8*>(&Ks[krow*64 + (ck ^ (krow&7))*8]);
        s[j] = __builtin_amdgcn_mfma_f32_16x16x32_bf16(a, bb, s[j], 0,0,0);
      }
    }

    #pragma unroll
    for (int r=0;r<4;r++)
      #pragma unroll
      for (int j=0;j<4;j++){
        float p = __expf(s[j][r]);       // Q pre-scaled by 0.125 in QKV GEMM
        s[j][r] = p;
        lp[r] += p;
      }

    #pragma unroll
    for (int j=0;j<4;j++)
      #pragma unroll
      for (int r=0;r<4;r++){
        int rowq = 16*wv + quad*4 + r;
        int key = l15 + 16*j;
        Ps[rowq*64 + (((key>>3) ^ ((rowq>>2)&7)))*8 + (key&7)] = f2bf(s[j][r]);
      }

    #pragma unroll
    for (int half=0; half<2; half++){
      const int ck = half*4 + quad;
      const int prow = 16*wv + l15;
      bf16x8 a = *reinterpret_cast<const bf16x8*>(&Ps[prow*64 + (ck ^ ((prow>>2)&7))*8]);
      #pragma unroll
      for (int jj=0;jj<4;jj++){
        int drow = 16*jj + l15;
        bf16x8 bb = *reinterpret_cast<const bf16x8*>(&Vt[drow*64 + (ck ^ (drow&7))*8]);
        acc[jj] = __builtin_amdgcn_mfma_f32_16x16x32_bf16(a, bb, acc[jj], 0,0,0);
      }
    }
    __syncthreads();   // all waves done reading Ks/Vt -> next iter may overwrite
  }

  #pragma unroll
  for (int r=0;r<4;r++){
    float l = lp[r];
    l += __shfl_xor(l, 1); l += __shfl_xor(l, 2);
    l += __shfl_xor(l, 4); l += __shfl_xor(l, 8);
    const float inv = 1.f / l;
    const int rloc = q0 + 16*wv + quad*4 + r;
    const long grow = rowbase + rloc;
    #pragma unroll
    for (int jj=0;jj<4;jj++)
      o[grow*256 + h*64 + 16*jj + l15] = f2bf(acc[jj][r]*inv);
  }
}

// ---------------- SE gate from column sums (4 lanes/output + shfl reduce); re-zeros cm ----------------
__global__ void segate2_k(float* __restrict__ cm, const float* __restrict__ w1,
                          const float* __restrict__ w2, float* __restrict__ gate){
  const int b = blockIdx.x, t = threadIdx.x;
  __shared__ float sc[256], sh[64];
  sc[t] = cm[b*256+t]*(1.f/1024.f);
  cm[b*256+t] = 0.f;                       // reset for next CS accumulation
  __syncthreads();
  {
    const int j = t >> 2, part = t & 3;    // 64 outputs x 4 lane-parts
    float a = 0.f;
    #pragma unroll 4
    for (int i=0;i<64;i++){
      const int k = i*4 + part;
      a += sc[k]*w1[k*64+j];
    }
    a += __shfl_xor(a, 1);
    a += __shfl_xor(a, 2);
    if (part == 0) sh[j] = fmaxf(a, 0.f);
  }
  __syncthreads();
  float a = 0.f;
  #pragma unroll 8
  for (int k=0;k<64;k++) a += sh[k]*w2[k*256+t];
  gate[b*256+t] = 1.f/(1.f+__expf(-a));
}

// ---------------- depthwise conv + BN + GELU, vectorized ----------------
__global__ void conv_bf_k(const unsigned short* __restrict__ y, unsigned short* __restrict__ z,
                          const float* __restrict__ cp)
{
  const int t = threadIdx.x;
  const int rr = t >> 6;
  const int row = blockIdx.x*4 + rr;
  const int n = row & 1023;
  const int c8 = (t & 63) * 8;
  const long base = (long)row*512 + c8;

  uint4 uc = *reinterpret_cast<const uint4*>(y + base);
  uint4 um = (n>0)    ? *reinterpret_cast<const uint4*>(y + base - 512) : uint4{0,0,0,0};
  uint4 up = (n<1023) ? *reinterpret_cast<const uint4*>(y + base + 512) : uint4{0,0,0,0};
  const unsigned short* yc = reinterpret_cast<const unsigned short*>(&uc);
  const unsigned short* ym = reinterpret_cast<const unsigned short*>(&um);
  const unsigned short* yp = reinterpret_cast<const unsigned short*>(&up);

  float c0[8], c1[8], c2[8], c3[8], s5[8], b5[8];
  #pragma unroll
  for (int q=0;q<8;q+=4){
    *reinterpret_cast<float4*>(&c0[q]) = *reinterpret_cast<const float4*>(cp + 0*512 + c8 + q);
    *reinterpret_cast<float4*>(&c1[q]) = *reinterpret_cast<const float4*>(cp + 1*512 + c8 + q);
    *reinterpret_cast<float4*>(&c2[q]) = *reinterpret_cast<const float4*>(cp + 2*512 + c8 + q);
    *reinterpret_cast<float4*>(&c3[q]) = *reinterpret_cast<const float4*>(cp + 3*512 + c8 + q);
    *reinterpret_cast<float4*>(&s5[q]) = *reinterpret_cast<const float4*>(cp + 4*512 + c8 + q);
    *reinterpret_cast<float4*>(&b5[q]) = *reinterpret_cast<const float4*>(cp + 5*512 + c8 + q);
  }

  unsigned short outv[8];
  #pragma unroll
  for (int q=0;q<8;q++){
    float zz = c0[q]*bf2f(ym[q]) + c1[q]*bf2f(yc[q]) + c2[q]*bf2f(yp[q]) + c3[q];
    zz = zz*s5[q] + b5[q];
    outv[q] = f2bf(gelu_f(zz));
  }
  *reinterpret_cast<uint4*>(z + base) = *reinterpret_cast<uint4*>(outv);
}

extern "C" void kernel_launch(void* const* d_in, const int* in_sizes, int n_in,
                              void* d_out, int out_size, void* d_ws, size_t ws_size,
                              hipStream_t stream)
{
  const float* x_in  = (const float*)d_in[0];
  const float* ln1_g = (const float*)d_in[1];
  const float* ln1_b = (const float*)d_in[2];
  const float* w_qkv = (const float*)d_in[3];
  const float* w_out = (const float*)d_in[4];
  const float* b_out = (const float*)d_in[5];
  const float* ln2_g = (const float*)d_in[6];
  const float* ln2_b = (const float*)d_in[7];
  const float* w_fc1 = (const float*)d_in[8];
  const float* b_fc1 = (const float*)d_in[9];
  const float* wh    = (const float*)d_in[10];
  const float* bh    = (const float*)d_in[11];
  const float* wv    = (const float*)d_in[12];
  const float* bv    = (const float*)d_in[13];
  const float* bn_g  = (const float*)d_in[14];
  const float* bn_b  = (const float*)d_in[15];
  const float* bn_m  = (const float*)d_in[16];
  const float* bn_v  = (const float*)d_in[17];
  const float* w_fc2 = (const float*)d_in[18];
  const float* b_fc2 = (const float*)d_in[19];
  const float* ls_w1 = (const float*)d_in[20];
  const float* ls_w2 = (const float*)d_in[21];

  float* ws   = (float*)d_ws;
  float* xbuf = ws;                        // 2,097,152 fl
  float* cm   = xbuf + 2097152;            // 2,048
  float* gate = cm + 2048;                 // 2,048
  float* cpar = gate + 2048;               // 6,144  [2][6][512]
  unsigned short* habf = (unsigned short*)(cpar + 6144);   // 2,097,152 u16
  unsigned short* qkb  = habf + 2097152;                   // 4,194,304 u16
  unsigned short* vtb  = qkb  + 4194304;                   // 2,097,152 u16
  unsigned short* ybf  = vtb  + 2097152;                   // 4,194,304 u16
  unsigned short* zbf  = ybf  + 4194304;                   // 4,194,304 u16
  unsigned short* wqkv_t = zbf + 4194304;
  unsigned short* wout_t = wqkv_t + 393216;
  unsigned short* wfc1_t = wout_t + 131072;
  unsigned short* wfc2_t = wfc1_t + 262144;

  tcast_all_k<<<2316,256,0,stream>>>(w_qkv, w_out, w_fc1, w_fc2,
                                     wqkv_t, wout_t, wfc1_t, wfc2_t,
                                     wh, bh, wv, bv, bn_g, bn_b, bn_m, bn_v, cpar, cm,
                                     x_in, ln1_g, ln1_b, habf);

  for (int l=0;l<2;l++){
    const float* bout_l = b_out + l*256;
    const float* bfc1_l = b_fc1 + l*512;
    const float* bfc2_l = b_fc2 + l*256;
    const float* lw1_l  = ls_w1 + (long)l*256*64;
    const float* lw2_l  = ls_w2 + (long)l*64*256;
    const float* resx   = (l==0) ? x_in : xbuf;

    // --- MHSA ---
    gmm_k<0,false,false,2,64,128,false><<<dim3(6,128),256,0,stream>>>(
        habf, wqkv_t + (long)l*768*256, (void*)qkb, 512, nullptr, nullptr, 256, vtb, nullptr);
    attn_k<<<dim3(16,32),256,0,stream>>>(qkb, vtb, habf);
    gmm_k<0,true,true,0,32,64,true><<<dim3(4,256),256,0,stream>>>(
        habf, wout_t + (long)l*256*256, (void*)xbuf, 256, bout_l, resx, 256, nullptr, cm);

    segate2_k<<<8,256,0,stream>>>(cm, lw1_l, lw2_l, gate);
    seapply_ln_k<<<2048,256,0,stream>>>(xbuf, gate, ln2_g + l*256, ln2_b + l*256, habf);

    // --- MLP ---
    gmm_k<1,false,true,1,64,64,false><<<dim3(8,128),256,0,stream>>>(
        habf, wfc1_t + (long)l*512*256, (void*)ybf, 512, bfc1_l, nullptr, 256, nullptr, nullptr);
    conv_bf_k<<<2048,256,0,stream>>>(ybf, zbf, cpar + (long)l*6*512);
    gmm_k<0,true,true,0,32,64,true><<<dim3(4,256),256,0,stream>>>(
        zbf, wfc2_t + (long)l*256*512, (void*)xbuf, 256, bfc2_l, xbuf, 512, nullptr, cm);

    segate2_k<<<8,256,0,stream>>>(cm, lw1_l, lw2_l, gate);
    if (l==0)
      seapply_ln_k<<<2048,256,0,stream>>>(xbuf, gate, ln1_g + 256, ln1_b + 256, habf);
    else
      seapply_out_k<<<2048,256,0,stream>>>(xbuf, gate, (float*)d_out);
  }
}